// Round 7
// baseline (156.119 us; speedup 1.0000x reference)
//
#include <hip/hip_runtime.h>

#define B_DIM 64
#define T_DIM 524288
#define D_FAC 16
#define NF 32768         // frames per row (T/D)
#define NFR_TOT 2097152  // total frames (B*NF)
#define LBLK 64          // frames per composed block
#define NB 512           // blocks per row
#define NCLS 65          // LBLK+1 slope classes
#define PF 16            // K2 prefetch depth (blocks)
#define EPSV 1e-7f
#define BIGC 1e30f

// 20*log10(2)
#define DB_PER_LOG2 6.0205999132796239f
// log2(10)/20
#define L2TEN_OVER20 0.16609640474436813f

__device__ __forceinline__ float sum_log2_4(float4 x) {
  return __log2f(fabsf(x.x) + EPSV) + __log2f(fabsf(x.y) + EPSV) +
         __log2f(fabsf(x.z) + EPSV) + __log2f(fabsf(x.w) + EPSV);
}

template <int CTRL, int RM>
__device__ __forceinline__ float fmin_dpp_step(float v) {
  int vi = __float_as_int(v);
  int sh = __builtin_amdgcn_update_dpp(vi, vi, CTRL, RM, 0xf, false);
  return fminf(v, __int_as_float(sh));
}

// K1a: streaming per-frame gain. One thread per frame, k3-style TLP
// (8192 WGs vs old k1's 512 -> fixes the latency-starved audio read).
__global__ __launch_bounds__(256) void k1a_gain(
    const float* __restrict__ audio, const float* __restrict__ p_thr,
    const float* __restrict__ p_ratio, float* __restrict__ g_out) {
  const int fr = blockIdx.x * 256 + threadIdx.x;  // frames tile [B][T] exactly
  const float thr = p_thr[0];
  const float gslope = (1.f / p_ratio[0]) - 1.f;
  const float4* ap = (const float4*)(audio + (size_t)fr * D_FAC);
  float s = 0.f;
#pragma unroll
  for (int q = 0; q < 4; ++q) s += sum_log2_4(ap[q]);
  float xdb = s * (DB_PER_LOG2 / 16.f);
  g_out[fr] = fminf(0.f, (xdb - thr) * gslope);
}

// K1b: DP-compose each 64-frame block into a 65-class min-affine map.
// One wave per WG (no dead waves); lane = block. g staged into LDS
// transposed [t][block] (stride 65 -> conflict-free reads AND writes).
// Two-pass named-scalar DP (r6-proven to stay in registers).
__global__ __launch_bounds__(64) void k1b_compose(
    const float* __restrict__ g_in, const float* __restrict__ p_att,
    const float* __restrict__ p_rel, float* __restrict__ consts) {
  __shared__ float gl2[64 * 65];   // [t][block], stride 65
  __shared__ float traj[64 * 64];  // [t][block-lane]
  const int lane = threadIdx.x;
  const int wg = blockIdx.x;  // 0..511, covers blocks wg*64..wg*64+63
  const float A = p_att[0], R = p_rel[0];
  const float oneA = 1.f - A, oneR = 1.f - R;
  const size_t gbase = (size_t)wg * 4096;

  // stage: lane l handles t=l for all 64 blocks; global reads coalesced.
#pragma unroll 4
  for (int i = 0; i < 64; ++i) {
    gl2[lane * 65 + i] = g_in[gbase + (size_t)i * 64 + lane];
  }
  __syncthreads();

  float* outp = consts + (size_t)(wg * 64 + lane) * NCLS;

#define U(a, b) c##a = fminf(fmaf(A, c##b, ca), fmaf(R, c##a, cr));

  // ---- pass 1: classes 0..32 ----
  {
    float c0 = 0.f;
    float c1 = BIGC, c2 = BIGC, c3 = BIGC, c4 = BIGC, c5 = BIGC, c6 = BIGC,
          c7 = BIGC, c8 = BIGC, c9 = BIGC, c10 = BIGC, c11 = BIGC, c12 = BIGC,
          c13 = BIGC, c14 = BIGC, c15 = BIGC, c16 = BIGC, c17 = BIGC,
          c18 = BIGC, c19 = BIGC, c20 = BIGC, c21 = BIGC, c22 = BIGC,
          c23 = BIGC, c24 = BIGC, c25 = BIGC, c26 = BIGC, c27 = BIGC,
          c28 = BIGC, c29 = BIGC, c30 = BIGC, c31 = BIGC, c32 = BIGC;
#pragma unroll 1
    for (int t = 0; t < LBLK; ++t) {
      float gt = gl2[t * 65 + lane];
      float ca = oneA * gt, cr = oneR * gt;
      traj[t * 64 + lane] = c32;  // pre-step boundary value for pass 2
      U(32, 31) U(31, 30) U(30, 29) U(29, 28) U(28, 27) U(27, 26) U(26, 25)
      U(25, 24) U(24, 23) U(23, 22) U(22, 21) U(21, 20) U(20, 19) U(19, 18)
      U(18, 17) U(17, 16) U(16, 15) U(15, 14) U(14, 13) U(13, 12) U(12, 11)
      U(11, 10) U(10, 9) U(9, 8) U(8, 7) U(7, 6) U(6, 5) U(5, 4) U(4, 3)
      U(3, 2) U(2, 1) U(1, 0)
      c0 = fmaf(R, c0, cr);
    }
#define S(a) outp[a] = c##a;
    S(0) S(1) S(2) S(3) S(4) S(5) S(6) S(7) S(8) S(9) S(10) S(11) S(12)
    S(13) S(14) S(15) S(16) S(17) S(18) S(19) S(20) S(21) S(22) S(23) S(24)
    S(25) S(26) S(27) S(28) S(29) S(30) S(31) S(32)
#undef S
  }

  // ---- pass 2: classes 33..64 ----
  {
    float c33 = BIGC, c34 = BIGC, c35 = BIGC, c36 = BIGC, c37 = BIGC,
          c38 = BIGC, c39 = BIGC, c40 = BIGC, c41 = BIGC, c42 = BIGC,
          c43 = BIGC, c44 = BIGC, c45 = BIGC, c46 = BIGC, c47 = BIGC,
          c48 = BIGC, c49 = BIGC, c50 = BIGC, c51 = BIGC, c52 = BIGC,
          c53 = BIGC, c54 = BIGC, c55 = BIGC, c56 = BIGC, c57 = BIGC,
          c58 = BIGC, c59 = BIGC, c60 = BIGC, c61 = BIGC, c62 = BIGC,
          c63 = BIGC, c64 = BIGC;
#pragma unroll 1
    for (int t = 0; t < LBLK; ++t) {
      float gt = gl2[t * 65 + lane];
      float ca = oneA * gt, cr = oneR * gt;
      float nb = traj[t * 64 + lane];  // c32 before step t
      U(64, 63) U(63, 62) U(62, 61) U(61, 60) U(60, 59) U(59, 58) U(58, 57)
      U(57, 56) U(56, 55) U(55, 54) U(54, 53) U(53, 52) U(52, 51) U(51, 50)
      U(50, 49) U(49, 48) U(48, 47) U(47, 46) U(46, 45) U(45, 44) U(44, 43)
      U(43, 42) U(42, 41) U(41, 40) U(40, 39) U(39, 38) U(38, 37) U(37, 36)
      U(36, 35) U(35, 34) U(34, 33)
      c33 = fminf(fmaf(A, nb, ca), fmaf(R, c33, cr));
    }
#define S(a) outp[a] = c##a;
    S(33) S(34) S(35) S(36) S(37) S(38) S(39) S(40) S(41) S(42) S(43) S(44)
    S(45) S(46) S(47) S(48) S(49) S(50) S(51) S(52) S(53) S(54) S(55) S(56)
    S(57) S(58) S(59) S(60) S(61) S(62) S(63) S(64)
#undef S
  }
#undef U
}

// K2: serial scan over 512 blocks per row. One wave per row; lane a holds
// slope class a (lane 63 also class 64). 16-deep register prefetch, no
// in-loop stores (states kept in regs, written at 64-step group ends).
__global__ __launch_bounds__(64) void k2_scan(const float* __restrict__ consts,
                                              float* __restrict__ states,
                                              const float* __restrict__ p_att,
                                              const float* __restrict__ p_rel) {
  const int r = blockIdx.x;
  const int lane = threadIdx.x;
  const float A = p_att[0], R = p_rel[0];
  float s = 1.f, sA = 1.f;
  for (int i = 0; i < 64; ++i) {
    s *= (i < lane) ? A : R;  // s = A^lane * R^(64-lane)
    sA *= A;                  // A^64
  }
  const bool last = (lane == 63);
  const float s2 = last ? sA : s;
  const int off1 = lane;
  const int off2 = last ? 64 : lane;
  const float* base = consts + (size_t)r * NB * NCLS;
  float* st = states + r * NB;
  float p = 0.f;

  float cb[PF], eb[PF];
#pragma unroll
  for (int u = 0; u < PF; ++u) {
    cb[u] = base[u * NCLS + off1];
    eb[u] = base[u * NCLS + off2];
  }

  for (int j = 0; j < 8; ++j) {       // 8 groups of 64 steps
    float sj = 0.f;                   // state slot: lane i holds block j*64+i
    for (int k = 0; k < 4; ++k) {     // 4 sub-groups of 16
#pragma unroll
      for (int u = 0; u < PF; ++u) {  // circular prefetch slot = u
        const int b = j * 64 + k * PF + u;
        const int i = k * PF + u;  // step within group (uniform)
        float f = fmaf(s, p, cb[u]);
        float e = fmaf(s2, p, eb[u]);
        float v = fminf(f, e);
        v = fmin_dpp_step<0x111, 0xf>(v);  // row_shr:1
        v = fmin_dpp_step<0x112, 0xf>(v);  // row_shr:2
        v = fmin_dpp_step<0x114, 0xf>(v);  // row_shr:4
        v = fmin_dpp_step<0x118, 0xf>(v);  // row_shr:8
        v = fmin_dpp_step<0x142, 0xa>(v);  // row_bcast:15
        v = fmin_dpp_step<0x143, 0xc>(v);  // row_bcast:31
        sj = (lane == i) ? p : sj;  // state at START of block b (old p)
        p = __int_as_float(
            __builtin_amdgcn_readlane(__float_as_int(v), 63));
        // refill slot u for block b+PF (buffer padded; no tail branch)
        cb[u] = base[(b + PF) * NCLS + off1];
        eb[u] = base[(b + PF) * NCLS + off2];
      }
    }
    st[j * 64 + lane] = sj;
  }
}

// K3: one wave per block. Each lane owns one frame (16 samples in regs),
// wave re-runs the 64-step recurrence from the block-start state via
// readlane broadcasts, then applies gain.
__global__ __launch_bounds__(256) void k3_apply(
    const float* __restrict__ audio, const float* __restrict__ states,
    const float* __restrict__ p_thr, const float* __restrict__ p_ratio,
    const float* __restrict__ p_makeup, const float* __restrict__ p_att,
    const float* __restrict__ p_rel, float* __restrict__ out) {
  const int tid = threadIdx.x;
  const int lane = tid & 63;
  const int w = tid >> 6;
  const int gblk = blockIdx.x * 4 + w;  // 0..32767
  const int row = gblk >> 9;
  const int b = gblk & (NB - 1);
  const float thr = p_thr[0], ratio = p_ratio[0], mk = p_makeup[0];
  const float A = p_att[0], R = p_rel[0];
  const float oneA = 1.f - A, oneR = 1.f - R;
  const float gslope = (1.f / ratio) - 1.f;

  const size_t sbase = (size_t)row * T_DIM + (size_t)(b * LBLK + lane) * D_FAC;
  const float4* ap = (const float4*)(audio + sbase);
  float4 x0 = ap[0], x1 = ap[1], x2 = ap[2], x3 = ap[3];
  float s = sum_log2_4(x0) + sum_log2_4(x1) + sum_log2_4(x2) + sum_log2_4(x3);
  float xdb = s * (DB_PER_LOG2 / 16.f);
  float g = fminf(0.f, (xdb - thr) * gslope);

  float p = states[gblk];
  float m = 0.f;
  int gi = __float_as_int(g);
#pragma unroll
  for (int t = 0; t < LBLK; ++t) {
    float gt = __int_as_float(__builtin_amdgcn_readlane(gi, t));
    p = fminf(fmaf(A, p, oneA * gt), fmaf(R, p, oneR * gt));
    m = (lane == t) ? p : m;
  }
  float mult = exp2f((m + mk) * L2TEN_OVER20);
  float4* op = (float4*)(out + sbase);
  float4 y0, y1, y2, y3;
  y0.x = x0.x * mult; y0.y = x0.y * mult; y0.z = x0.z * mult; y0.w = x0.w * mult;
  y1.x = x1.x * mult; y1.y = x1.y * mult; y1.z = x1.z * mult; y1.w = x1.w * mult;
  y2.x = x2.x * mult; y2.y = x2.y * mult; y2.z = x2.z * mult; y2.w = x2.w * mult;
  y3.x = x3.x * mult; y3.y = x3.y * mult; y3.z = x3.z * mult; y3.w = x3.w * mult;
  op[0] = y0; op[1] = y1; op[2] = y2; op[3] = y3;
}

extern "C" void kernel_launch(void* const* d_in, const int* in_sizes, int n_in,
                              void* d_out, int out_size, void* d_ws,
                              size_t ws_size, hipStream_t stream) {
  const float* audio = (const float*)d_in[0];
  const float* thr = (const float*)d_in[1];
  const float* ratio = (const float*)d_in[2];
  const float* makeup = (const float*)d_in[3];
  const float* att = (const float*)d_in[4];
  const float* rel = (const float*)d_in[5];
  float* out = (float*)d_out;

  const size_t G_BYTES = (size_t)NFR_TOT * sizeof(float);                 // 8.4 MB
  const size_t CONSTS_BYTES = (size_t)B_DIM * NB * NCLS * sizeof(float);  // ~8.5 MB
  const size_t PAD_BYTES = (size_t)PF * NCLS * sizeof(float);             // tail prefetch pad
  const size_t STATES_BYTES = (size_t)B_DIM * NB * sizeof(float);         // 128 KB

  float* gbuf;
  float* consts;
  float* states;
  if (ws_size >= G_BYTES + CONSTS_BYTES + PAD_BYTES + STATES_BYTES) {
    gbuf = (float*)d_ws;
    consts = (float*)((char*)d_ws + G_BYTES);
    states = (float*)((char*)d_ws + G_BYTES + CONSTS_BYTES + PAD_BYTES);
  } else {
    // d_out (128 MB) as scratch for g + consts: both dead before K3 runs,
    // and K3 overwrites every byte of d_out. states (128 KB) in ws.
    gbuf = (float*)d_out;
    consts = (float*)((char*)d_out + G_BYTES);
    states = (float*)d_ws;
  }

  hipLaunchKernelGGL(k1a_gain, dim3(8192), dim3(256), 0, stream, audio, thr,
                     ratio, gbuf);
  hipLaunchKernelGGL(k1b_compose, dim3(512), dim3(64), 0, stream, gbuf, att,
                     rel, consts);
  hipLaunchKernelGGL(k2_scan, dim3(64), dim3(64), 0, stream, consts, states,
                     att, rel);
  hipLaunchKernelGGL(k3_apply, dim3(8192), dim3(256), 0, stream, audio, states,
                     thr, ratio, makeup, att, rel, out);
}

// Round 8
// 148.453 us; speedup vs baseline: 1.0516x; 1.0516x over previous
//
#include <hip/hip_runtime.h>

#define B_DIM 64
#define T_DIM 524288
#define D_FAC 16
#define NF 32768         // frames per row (T/D)
#define LBLK 64          // frames per composed block
#define NB 512           // blocks per row
#define NCLS 65          // LBLK+1 slope classes
#define PF 16            // K2 prefetch depth (blocks)
#define EPSV 1e-7f
#define BIGC 1e30f

// 20*log10(2)
#define DB_PER_LOG2 6.0205999132796239f
// log2(10)/20
#define L2TEN_OVER20 0.16609640474436813f

__device__ __forceinline__ float sum_log2_4(float4 x) {
  return __log2f(fabsf(x.x) + EPSV) + __log2f(fabsf(x.y) + EPSV) +
         __log2f(fabsf(x.z) + EPSV) + __log2f(fabsf(x.w) + EPSV);
}

template <int CTRL, int RM>
__device__ __forceinline__ float fmin_dpp_step(float v) {
  int vi = __float_as_int(v);
  int sh = __builtin_amdgcn_update_dpp(vi, vi, CTRL, RM, 0xf, false);
  return fminf(v, __int_as_float(sh));
}

// K1: one wave per 64-frame block. Phase 1 (lane = frame): k3-style audio
// read + per-frame gain g. Phase 2 (lane = CLASS): the DP update
//   c_new[a] = min(A*c_old[a-1]+ca, R*c_old[a]+cr)
// reads only old values -> parallel across classes via DPP wave_shr:1.
// Dependent chain = 3 VALU/step (vs 97 serial ops in r4-r7), at full
// occupancy (32768 waves vs r6's 2 waves/CU).
__global__ __launch_bounds__(256) void k1_compose(
    const float* __restrict__ audio, const float* __restrict__ p_thr,
    const float* __restrict__ p_ratio, const float* __restrict__ p_att,
    const float* __restrict__ p_rel, float* __restrict__ consts) {
  const int tid = threadIdx.x;
  const int lane = tid & 63;
  const int w = tid >> 6;
  const int gblk = blockIdx.x * 4 + w;  // 0..32767
  const int row = gblk >> 9;
  const int b = gblk & (NB - 1);
  const float thr = p_thr[0];
  const float A = p_att[0], R = p_rel[0];
  const float oneA = 1.f - A, oneR = 1.f - R;
  const float gslope = (1.f / p_ratio[0]) - 1.f;

  const size_t sbase = (size_t)row * T_DIM + (size_t)(b * LBLK + lane) * D_FAC;
  const float4* ap = (const float4*)(audio + sbase);
  float s = sum_log2_4(ap[0]) + sum_log2_4(ap[1]) + sum_log2_4(ap[2]) +
            sum_log2_4(ap[3]);
  float xdb = s * (DB_PER_LOG2 / 16.f);
  float g = fminf(0.f, (xdb - thr) * gslope);
  const int gi = __float_as_int(g);

  // DP over t: lane a holds class a; class 64 carried redundantly by all
  // lanes (only lane 63's value is real -> it sees c63_old before update).
  float c = (lane == 0) ? 0.f : BIGC;
  float c64 = BIGC;
#pragma unroll
  for (int t = 0; t < LBLK; ++t) {
    float gt = __int_as_float(__builtin_amdgcn_readlane(gi, t));
    float ca = oneA * gt, cr = oneR * gt;
    // prev = c_old[lane-1]; lane 0 keeps old=BIGC (class -1 absent ->
    // A-branch loses the min).
    float prev = __int_as_float(__builtin_amdgcn_update_dpp(
        __float_as_int(BIGC), __float_as_int(c), 0x138 /*wave_shr:1*/, 0xf,
        0xf, false));
    c64 = fminf(fmaf(A, c, ca), fmaf(R, c64, cr));  // uses c63_old on lane 63
    c = fminf(fmaf(A, prev, ca), fmaf(R, c, cr));
  }
  float* outp = consts + (size_t)gblk * NCLS;
  outp[lane] = c;
  if (lane == 63) outp[64] = c64;
}

// K2: serial scan over 512 blocks per row. One wave per row; lane a holds
// slope class a (lane 63 also class 64). 16-deep register prefetch, no
// in-loop stores (states kept in regs, written at 64-step group ends).
__global__ __launch_bounds__(64) void k2_scan(const float* __restrict__ consts,
                                              float* __restrict__ states,
                                              const float* __restrict__ p_att,
                                              const float* __restrict__ p_rel) {
  const int r = blockIdx.x;
  const int lane = threadIdx.x;
  const float A = p_att[0], R = p_rel[0];
  float s = 1.f, sA = 1.f;
  for (int i = 0; i < 64; ++i) {
    s *= (i < lane) ? A : R;  // s = A^lane * R^(64-lane)
    sA *= A;                  // A^64
  }
  const bool last = (lane == 63);
  const float s2 = last ? sA : s;
  const int off1 = lane;
  const int off2 = last ? 64 : lane;
  const float* base = consts + (size_t)r * NB * NCLS;
  float* st = states + r * NB;
  float p = 0.f;

  float cb[PF], eb[PF];
#pragma unroll
  for (int u = 0; u < PF; ++u) {
    cb[u] = base[u * NCLS + off1];
    eb[u] = base[u * NCLS + off2];
  }

  for (int j = 0; j < 8; ++j) {       // 8 groups of 64 steps
    float sj = 0.f;                   // state slot: lane i holds block j*64+i
    for (int k = 0; k < 4; ++k) {     // 4 sub-groups of 16
#pragma unroll
      for (int u = 0; u < PF; ++u) {  // circular prefetch slot = u
        const int b = j * 64 + k * PF + u;
        const int i = k * PF + u;  // step within group (uniform)
        float f = fmaf(s, p, cb[u]);
        float e = fmaf(s2, p, eb[u]);
        float v = fminf(f, e);
        v = fmin_dpp_step<0x111, 0xf>(v);  // row_shr:1
        v = fmin_dpp_step<0x112, 0xf>(v);  // row_shr:2
        v = fmin_dpp_step<0x114, 0xf>(v);  // row_shr:4
        v = fmin_dpp_step<0x118, 0xf>(v);  // row_shr:8
        v = fmin_dpp_step<0x142, 0xa>(v);  // row_bcast:15
        v = fmin_dpp_step<0x143, 0xc>(v);  // row_bcast:31
        sj = (lane == i) ? p : sj;  // state at START of block b (old p)
        p = __int_as_float(
            __builtin_amdgcn_readlane(__float_as_int(v), 63));
        // refill slot u for block b+PF (buffer padded; no tail branch)
        cb[u] = base[(b + PF) * NCLS + off1];
        eb[u] = base[(b + PF) * NCLS + off2];
      }
    }
    st[j * 64 + lane] = sj;
  }
}

// K3: one wave per block. Each lane owns one frame (16 samples in regs),
// wave re-runs the 64-step recurrence from the block-start state via
// readlane broadcasts, then applies gain.
__global__ __launch_bounds__(256) void k3_apply(
    const float* __restrict__ audio, const float* __restrict__ states,
    const float* __restrict__ p_thr, const float* __restrict__ p_ratio,
    const float* __restrict__ p_makeup, const float* __restrict__ p_att,
    const float* __restrict__ p_rel, float* __restrict__ out) {
  const int tid = threadIdx.x;
  const int lane = tid & 63;
  const int w = tid >> 6;
  const int gblk = blockIdx.x * 4 + w;  // 0..32767
  const int row = gblk >> 9;
  const int b = gblk & (NB - 1);
  const float thr = p_thr[0], ratio = p_ratio[0], mk = p_makeup[0];
  const float A = p_att[0], R = p_rel[0];
  const float oneA = 1.f - A, oneR = 1.f - R;
  const float gslope = (1.f / ratio) - 1.f;

  const size_t sbase = (size_t)row * T_DIM + (size_t)(b * LBLK + lane) * D_FAC;
  const float4* ap = (const float4*)(audio + sbase);
  float4 x0 = ap[0], x1 = ap[1], x2 = ap[2], x3 = ap[3];
  float s = sum_log2_4(x0) + sum_log2_4(x1) + sum_log2_4(x2) + sum_log2_4(x3);
  float xdb = s * (DB_PER_LOG2 / 16.f);
  float g = fminf(0.f, (xdb - thr) * gslope);

  float p = states[gblk];
  float m = 0.f;
  int gi = __float_as_int(g);
#pragma unroll
  for (int t = 0; t < LBLK; ++t) {
    float gt = __int_as_float(__builtin_amdgcn_readlane(gi, t));
    p = fminf(fmaf(A, p, oneA * gt), fmaf(R, p, oneR * gt));
    m = (lane == t) ? p : m;
  }
  float mult = exp2f((m + mk) * L2TEN_OVER20);
  float4* op = (float4*)(out + sbase);
  float4 y0, y1, y2, y3;
  y0.x = x0.x * mult; y0.y = x0.y * mult; y0.z = x0.z * mult; y0.w = x0.w * mult;
  y1.x = x1.x * mult; y1.y = x1.y * mult; y1.z = x1.z * mult; y1.w = x1.w * mult;
  y2.x = x2.x * mult; y2.y = x2.y * mult; y2.z = x2.z * mult; y2.w = x2.w * mult;
  y3.x = x3.x * mult; y3.y = x3.y * mult; y3.z = x3.z * mult; y3.w = x3.w * mult;
  op[0] = y0; op[1] = y1; op[2] = y2; op[3] = y3;
}

extern "C" void kernel_launch(void* const* d_in, const int* in_sizes, int n_in,
                              void* d_out, int out_size, void* d_ws,
                              size_t ws_size, hipStream_t stream) {
  const float* audio = (const float*)d_in[0];
  const float* thr = (const float*)d_in[1];
  const float* ratio = (const float*)d_in[2];
  const float* makeup = (const float*)d_in[3];
  const float* att = (const float*)d_in[4];
  const float* rel = (const float*)d_in[5];
  float* out = (float*)d_out;

  const size_t CONSTS_BYTES = (size_t)B_DIM * NB * NCLS * sizeof(float);  // ~8.5 MB
  const size_t PAD_BYTES = (size_t)PF * NCLS * sizeof(float);             // tail prefetch pad
  const size_t STATES_BYTES = (size_t)B_DIM * NB * sizeof(float);         // 128 KB

  float* consts;
  float* states;
  if (ws_size >= CONSTS_BYTES + PAD_BYTES + STATES_BYTES) {
    consts = (float*)d_ws;
    states = (float*)((char*)d_ws + CONSTS_BYTES + PAD_BYTES);
  } else {
    // d_out (128 MB) as scratch for consts: only live during K1->K2, and K3
    // overwrites every byte of d_out afterwards. states (128 KB) in ws.
    consts = (float*)d_out;
    states = (float*)d_ws;
  }

  hipLaunchKernelGGL(k1_compose, dim3(8192), dim3(256), 0, stream, audio, thr,
                     ratio, att, rel, consts);
  hipLaunchKernelGGL(k2_scan, dim3(64), dim3(64), 0, stream, consts, states,
                     att, rel);
  hipLaunchKernelGGL(k3_apply, dim3(8192), dim3(256), 0, stream, audio, states,
                     thr, ratio, makeup, att, rel, out);
}

// Round 10
// 142.337 us; speedup vs baseline: 1.0968x; 1.0430x over previous
//
#include <hip/hip_runtime.h>

#define B_DIM 64
#define T_DIM 524288
#define D_FAC 16
#define LBLK 64          // frames per composed block
#define NB 512           // blocks per row
#define NBLK_TOT 32768   // total blocks (B*NB)
#define CSTR 72          // padded stride (floats) of one block map (16B-aligned)
#define PF 8             // K2 prefetch depth (blocks)
#define EPSV 1e-7f
#define BIGC 1e30f

// 20*log10(2)
#define DB_PER_LOG2 6.0205999132796239f
// log2(10)/20
#define L2TEN_OVER20 0.16609640474436813f

__device__ __forceinline__ float sum_log2_4(float4 x) {
  return __log2f(fabsf(x.x) + EPSV) + __log2f(fabsf(x.y) + EPSV) +
         __log2f(fabsf(x.z) + EPSV) + __log2f(fabsf(x.w) + EPSV);
}

template <int CTRL, int RM>
__device__ __forceinline__ float fmin_dpp_step(float v) {
  int vi = __float_as_int(v);
  int sh = __builtin_amdgcn_update_dpp(vi, vi, CTRL, RM, 0xf, false);
  return fminf(v, __int_as_float(sh));
}

// K1: one wave per 64-frame block (r8 version, passing at ~74us).
// lane = class; c_new[a] = min(A*c_old[a-1]+ca, R*c_old[a]+cr) via DPP
// wave_shr:1. Stride CSTR=72; class 64 replicated into slots 64..71 so
// K2's lane 8 can read it as two float4.
__global__ __launch_bounds__(256) void k1_compose(
    const float* __restrict__ audio, const float* __restrict__ p_thr,
    const float* __restrict__ p_ratio, const float* __restrict__ p_att,
    const float* __restrict__ p_rel, float* __restrict__ consts) {
  const int tid = threadIdx.x;
  const int lane = tid & 63;
  const int w = tid >> 6;
  const int gblk = blockIdx.x * 4 + w;  // 0..32767
  const int row = gblk >> 9;
  const int b = gblk & (NB - 1);
  const float thr = p_thr[0];
  const float A = p_att[0], R = p_rel[0];
  const float oneA = 1.f - A, oneR = 1.f - R;
  const float gslope = (1.f / p_ratio[0]) - 1.f;

  const size_t sbase = (size_t)row * T_DIM + (size_t)(b * LBLK + lane) * D_FAC;
  const float4* ap = (const float4*)(audio + sbase);
  float s = sum_log2_4(ap[0]) + sum_log2_4(ap[1]) + sum_log2_4(ap[2]) +
            sum_log2_4(ap[3]);
  float xdb = s * (DB_PER_LOG2 / 16.f);
  float g = fminf(0.f, (xdb - thr) * gslope);
  const int gi = __float_as_int(g);

  float c = (lane == 0) ? 0.f : BIGC;
  float c64 = BIGC;
#pragma unroll
  for (int t = 0; t < LBLK; ++t) {
    float gt = __int_as_float(__builtin_amdgcn_readlane(gi, t));
    float ca = oneA * gt, cr = oneR * gt;
    float prev = __int_as_float(__builtin_amdgcn_update_dpp(
        __float_as_int(BIGC), __float_as_int(c), 0x138 /*wave_shr:1*/, 0xf,
        0xf, false));
    c64 = fminf(fmaf(A, c, ca), fmaf(R, c64, cr));  // uses c63_old on lane 63
    c = fminf(fmaf(A, prev, ca), fmaf(R, c, cr));
  }
  float* outp = consts + (size_t)gblk * CSTR;
  outp[lane] = c;
  if (lane == 63) {
#pragma unroll
    for (int j = 0; j < 8; ++j) outp[64 + j] = c64;
  }
}

// K2: serial scan, one wave per row. 8 classes per lane: lane l in [0,8)
// holds classes 8l..8l+7 (two float4); lane 8 holds class 64 (replicated).
// Per step: 8 fma + local min tree + 4 DPP stages + readlane(8) --
// vs 6 DPP stages + 2-class work before (cuts the ~240cyc/step chain).
// Lanes 9..63 compute garbage that no reduce stage at lane<=8 reads
// (row_shr pulls only from lower lanes); their loads alias lane 8's line.
// p stays <= 0 (all c <= 0), so lane 8's extra slots (smaller slopes,
// same c64) give f >= the true class-64 value and never win the min.
__global__ __launch_bounds__(64) void k2_scan(const float* __restrict__ consts,
                                              float* __restrict__ states,
                                              const float* __restrict__ p_att,
                                              const float* __restrict__ p_rel) {
  const int r = blockIdx.x;
  const int lane = threadIdx.x;
  const float A = p_att[0], R = p_rel[0];
  const int cls0 = (lane < 8) ? 8 * lane : 64;
  float s0 = 1.f;
  for (int i = 0; i < 64; ++i) s0 *= (i < cls0) ? A : R;  // A^cls0 R^(64-cls0)
  const float rAR = A / R;
  const float sl0 = s0, sl1 = sl0 * rAR, sl2 = sl1 * rAR, sl3 = sl2 * rAR,
              sl4 = sl3 * rAR, sl5 = sl4 * rAR, sl6 = sl5 * rAR,
              sl7 = sl6 * rAR;

  const float* base = consts + (size_t)r * NB * CSTR;
  float* st = states + r * NB;
  const int loff = (lane < 8) ? 8 * lane : 64;

  float4 qa[PF], qb[PF];
#pragma unroll
  for (int u = 0; u < PF; ++u) {
    qa[u] = *(const float4*)(base + u * CSTR + loff);
    qb[u] = *(const float4*)(base + u * CSTR + loff + 4);
  }

  float p = 0.f;
  for (int j = 0; j < 8; ++j) {       // 8 groups of 64 steps
    float sj = 0.f;                   // lane i holds state of block j*64+i
    for (int k = 0; k < 8; ++k) {     // 8 sub-groups of PF=8
#pragma unroll
      for (int u = 0; u < PF; ++u) {
        const int b = j * 64 + k * PF + u;
        const int i = k * PF + u;  // step within group (uniform)
        float f0 = fmaf(sl0, p, qa[u].x);
        float f1 = fmaf(sl1, p, qa[u].y);
        float f2 = fmaf(sl2, p, qa[u].z);
        float f3 = fmaf(sl3, p, qa[u].w);
        float f4 = fmaf(sl4, p, qb[u].x);
        float f5 = fmaf(sl5, p, qb[u].y);
        float f6 = fmaf(sl6, p, qb[u].z);
        float f7 = fmaf(sl7, p, qb[u].w);
        float m = fminf(fminf(fminf(f0, f1), f2),
                        fminf(fminf(fminf(f3, f4), f5), fminf(f6, f7)));
        m = fmin_dpp_step<0x111, 0xf>(m);  // row_shr:1
        m = fmin_dpp_step<0x112, 0xf>(m);  // row_shr:2
        m = fmin_dpp_step<0x114, 0xf>(m);  // row_shr:4 -> lane7 = min(0..7)
        m = fmin_dpp_step<0x111, 0xf>(m);  // fold lane7 agg into lane8
        sj = (lane == i) ? p : sj;  // state at START of block b (old p)
        p = __int_as_float(__builtin_amdgcn_readlane(__float_as_int(m), 8));
        // refill slot u for block b+PF (buffer padded; no tail branch)
        qa[u] = *(const float4*)(base + (b + PF) * CSTR + loff);
        qb[u] = *(const float4*)(base + (b + PF) * CSTR + loff + 4);
      }
    }
    st[j * 64 + lane] = sj;
  }
}

// K3: one wave per block; lane owns one frame (16 samples in regs); wave
// replays the 64-step recurrence from the block-start state; applies gain.
__global__ __launch_bounds__(256) void k3_apply(
    const float* __restrict__ audio, const float* __restrict__ states,
    const float* __restrict__ p_thr, const float* __restrict__ p_ratio,
    const float* __restrict__ p_makeup, const float* __restrict__ p_att,
    const float* __restrict__ p_rel, float* __restrict__ out) {
  const int tid = threadIdx.x;
  const int lane = tid & 63;
  const int w = tid >> 6;
  const int gblk = blockIdx.x * 4 + w;  // 0..32767
  const int row = gblk >> 9;
  const int b = gblk & (NB - 1);
  const float thr = p_thr[0], ratio = p_ratio[0], mk = p_makeup[0];
  const float A = p_att[0], R = p_rel[0];
  const float oneA = 1.f - A, oneR = 1.f - R;
  const float gslope = (1.f / ratio) - 1.f;

  const size_t sbase = (size_t)row * T_DIM + (size_t)(b * LBLK + lane) * D_FAC;
  const float4* ap = (const float4*)(audio + sbase);
  float4 x0 = ap[0], x1 = ap[1], x2 = ap[2], x3 = ap[3];
  float s = sum_log2_4(x0) + sum_log2_4(x1) + sum_log2_4(x2) + sum_log2_4(x3);
  float xdb = s * (DB_PER_LOG2 / 16.f);
  float g = fminf(0.f, (xdb - thr) * gslope);

  float p = states[gblk];
  float m = 0.f;
  int gi = __float_as_int(g);
#pragma unroll
  for (int t = 0; t < LBLK; ++t) {
    float gt = __int_as_float(__builtin_amdgcn_readlane(gi, t));
    p = fminf(fmaf(A, p, oneA * gt), fmaf(R, p, oneR * gt));
    m = (lane == t) ? p : m;
  }
  float mult = exp2f((m + mk) * L2TEN_OVER20);
  float4* op = (float4*)(out + sbase);
  float4 y0, y1, y2, y3;
  y0.x = x0.x * mult; y0.y = x0.y * mult; y0.z = x0.z * mult; y0.w = x0.w * mult;
  y1.x = x1.x * mult; y1.y = x1.y * mult; y1.z = x1.z * mult; y1.w = x1.w * mult;
  y2.x = x2.x * mult; y2.y = x2.y * mult; y2.z = x2.z * mult; y2.w = x2.w * mult;
  y3.x = x3.x * mult; y3.y = x3.y * mult; y3.z = x3.z * mult; y3.w = x3.w * mult;
  op[0] = y0; op[1] = y1; op[2] = y2; op[3] = y3;
}

extern "C" void kernel_launch(void* const* d_in, const int* in_sizes, int n_in,
                              void* d_out, int out_size, void* d_ws,
                              size_t ws_size, hipStream_t stream) {
  const float* audio = (const float*)d_in[0];
  const float* thr = (const float*)d_in[1];
  const float* ratio = (const float*)d_in[2];
  const float* makeup = (const float*)d_in[3];
  const float* att = (const float*)d_in[4];
  const float* rel = (const float*)d_in[5];
  float* out = (float*)d_out;

  const size_t CONSTS_BYTES = (size_t)NBLK_TOT * CSTR * sizeof(float);  // ~9.4 MB
  const size_t PAD_BYTES = (size_t)PF * CSTR * sizeof(float);           // tail prefetch pad
  const size_t STATES_BYTES = (size_t)NBLK_TOT * sizeof(float);         // 128 KB

  float* consts;
  float* states;
  if (ws_size >= CONSTS_BYTES + PAD_BYTES + STATES_BYTES) {
    consts = (float*)d_ws;
    states = (float*)((char*)d_ws + CONSTS_BYTES + PAD_BYTES);
  } else {
    // d_out (128 MB) as scratch for consts: only live during K1->K2, and K3
    // overwrites every byte of d_out afterwards. states (128 KB) in ws.
    consts = (float*)d_out;
    states = (float*)d_ws;
  }

  hipLaunchKernelGGL(k1_compose, dim3(8192), dim3(256), 0, stream, audio, thr,
                     ratio, att, rel, consts);
  hipLaunchKernelGGL(k2_scan, dim3(64), dim3(64), 0, stream, consts, states,
                     att, rel);
  hipLaunchKernelGGL(k3_apply, dim3(8192), dim3(256), 0, stream, audio, states,
                     thr, ratio, makeup, att, rel, out);
}